// Round 4
// baseline (152.139 us; speedup 1.0000x reference)
//
#include <hip/hip_runtime.h>
#include <hip/hip_bf16.h>
#include <cstdint>

typedef __attribute__((ext_vector_type(4))) float f32x4;
typedef __attribute__((ext_vector_type(8))) short s16x8;

#define LOG2E 1.4426950408889634f
#define RESC_THR 8.0f

#define B_   4
#define C_   256
#define N_   4096
#define NT_  256    // 16-pixel tiles per batch
#define MB_  128    // 32-key blocks per batch

// workspace byte offsets
#define WS_WFRAG 0u          // 20*8*4*16*8 bf16   = 163840
#define WS_BIAS  163840u     // 320 f32            = 1280
#define WS_Q     262144u     // B*N*32 bf16        = 1 MiB
#define WS_K     1310720u    // 1 MiB
#define WS_V     2359296u    // B*N*256 bf16       = 8 MiB  (end 10747904)

__device__ __forceinline__ short bf16s(float f) {
  return (short)__bfloat16_as_ushort(__float2bfloat16(f));
}

// ---------------- pack W (320x256) into A-frag layout, gather bias ----------------
// frag index d = (((t*8 + ks)*4 + g)*16 + c)*8 + j
//   lane (g,c) elem j holds W[o = t*16 + c][ch = ks*32 + g*8 + j]
__global__ void wprep_kernel(const float* __restrict__ Wq, const float* __restrict__ Wk,
                             const float* __restrict__ Wv, const float* __restrict__ bq,
                             const float* __restrict__ bk, const float* __restrict__ bv,
                             short* __restrict__ wfrag, float* __restrict__ bias) {
  int d0 = blockIdx.x * 256 + threadIdx.x;         // 81920 = 20*8*4*16*8
  int d = d0;
  int j  = d & 7;  d >>= 3;
  int c  = d & 15; d >>= 4;
  int g  = d & 3;  d >>= 2;
  int ks = d & 7;  d >>= 3;
  int t  = d;
  int o  = t * 16 + c;
  int ch = ks * 32 + g * 8 + j;
  float w = (o < 32) ? Wq[o * 256 + ch] : (o < 64) ? Wk[(o - 32) * 256 + ch]
                                                   : Wv[(o - 64) * 256 + ch];
  wfrag[d0] = bf16s(w);
  if (d0 < 320) bias[d0] = (d0 < 32) ? bq[d0] : (d0 < 64) ? bk[d0 - 32] : bv[d0 - 64];
}

// ---------------- fused QKV projection (MFMA) + inline gate + swizzled stores ----------------
__global__ __launch_bounds__(256) void proj_kernel(
    const float* __restrict__ x, const short* __restrict__ wfrag,
    const float* __restrict__ bias, const float* __restrict__ gm,
    short* __restrict__ qs, short* __restrict__ ksz, short* __restrict__ vs) {
  int b = blockIdx.x >> 8, nt = blockIdx.x & 255;
  int lane = threadIdx.x & 63, wave = threadIdx.x >> 6;
  int g = lane >> 4, c = lane & 15;
  int n = nt * 16 + c;

  // inline gate: bilinear align-corners 32->64 + sigmoid, one pixel per thread
  float gt;
  {
    int y = n >> 6, xp = n & 63;
    float fy = (float)(y * 31) / 63.0f;
    float fx = (float)(xp * 31) / 63.0f;
    int y0 = (int)fy, x0 = (int)fx;
    float wy = fy - (float)y0, wx = fx - (float)x0;
    int y1 = min(y0 + 1, 31), x1 = min(x0 + 1, 31);
    const float* p = gm + b * 1024;
    float v00 = p[y0 * 32 + x0], v01 = p[y0 * 32 + x1];
    float v10 = p[y1 * 32 + x0], v11 = p[y1 * 32 + x1];
    float top = v00 * (1.f - wx) + v01 * wx;
    float bot = v10 * (1.f - wx) + v11 * wx;
    float gv  = top * (1.f - wy) + bot * wy;
    gt = 1.0f + 1.0f / (1.0f + expf(-gv));
  }

  // X B-fragments for all 8 k-steps: lane holds x[b][ks*32+g*8+j][n]
  const float* xb = x + b * (C_ * N_) + n;
  s16x8 xf[8];
  #pragma unroll
  for (int ks = 0; ks < 8; ++ks) {
    int ch0 = ks * 32 + g * 8;
    s16x8 v;
    #pragma unroll
    for (int j = 0; j < 8; ++j) v[j] = bf16s(xb[(ch0 + j) * N_]);
    xf[ks] = v;
  }

  for (int t = wave * 5; t < wave * 5 + 5; ++t) {
    f32x4 acc = {0.f, 0.f, 0.f, 0.f};
    #pragma unroll
    for (int ks = 0; ks < 8; ++ks) {
      s16x8 wf = *(const s16x8*)(wfrag + ((((t * 8 + ks) * 4 + g) * 16 + c) * 8));
      acc = __builtin_amdgcn_mfma_f32_16x16x32_bf16(wf, xf[ks], acc, 0, 0, 0);
    }
    #pragma unroll
    for (int jj = 0; jj < 4; ++jj) {
      int o = t * 16 + g * 4 + jj;                 // D row = (lane>>4)*4+reg
      float val = (acc[jj] + bias[o]) * gt;        // D col = lane&15 = pixel
      short bv16 = bf16s(val);
      if (o < 64) {                                 // Q or K: [b][nt][ch>>3][c][ch&7]
        int ch = o & 31;
        short* dst = (o < 32) ? qs : ksz;
        dst[(((b * NT_ + nt) * 4 + (ch >> 3)) * 16 + c) * 8 + (ch & 7)] = bv16;
      } else {                                      // V: [b][mb][ct][g'][c'][j']
        int cv = o - 64;
        int mb = n >> 5, r = n & 31;
        int jp = ((r >> 4) << 2) + (r & 3), gp = (r >> 2) & 3;
        vs[((((b * MB_ + mb) * 16 + (cv >> 4)) * 4 + gp) * 16 + (cv & 15)) * 8 + jp] = bv16;
      }
    }
  }
}

// ---------------- flash attention, split-KV within block, defer-rescale ----------------
// 1024 blocks, 4 waves each. Block owns one 16-query tile; wave w processes
// kv-blocks mb = w + 4*i (32 iters), private (m,l,acc). K/V stream from L2.
__global__ __launch_bounds__(256) void attn_kernel(
    const short* __restrict__ qs, const short* __restrict__ ksz,
    const short* __restrict__ vs, const float* __restrict__ x,
    const float* __restrict__ gamma, float* __restrict__ out) {
  __shared__ float comb_m[4][64];
  __shared__ float comb_l[4][64];
  __shared__ __align__(16) float sumbuf[4][4][64][4];   // 16 KB

  int bid = blockIdx.x;
  // XCD-aware decode: XCD = bid%8; batch b -> XCDs {2b,2b+1}
  int b  = (bid & 7) >> 1;
  int qt = ((bid >> 3) << 1) | (bid & 1);               // 0..255
  int tid = threadIdx.x;
  int lane = tid & 63, wave = tid >> 6;
  int g = lane >> 4, c = lane & 15;

  s16x8 qf = *(const s16x8*)(qs + (((b * NT_ + qt) * 4 + g) * 16 + c) * 8);

  f32x4 acc[16];
  #pragma unroll
  for (int i = 0; i < 16; ++i) acc[i] = (f32x4){0.f, 0.f, 0.f, 0.f};
  float m = -3.0e38f, lsum = 0.f;

  const short* kb0 = ksz + (size_t)b * (MB_ * 1024) + ((g * 16 + c) * 8);
  const short* vb0 = vs  + (size_t)b * (MB_ * 8192) + ((g * 16 + c) * 8);

  for (int i = 0; i < 32; ++i) {
    int mb = wave + i * 4;
    const short* kb = kb0 + mb * 1024;
    const short* vb = vb0 + mb * 8192;

    s16x8 kf0 = *(const s16x8*)(kb);
    s16x8 kf1 = *(const s16x8*)(kb + 512);          // ks=1: +4*16*8
    f32x4 z = {0.f, 0.f, 0.f, 0.f};
    f32x4 st0 = __builtin_amdgcn_mfma_f32_16x16x32_bf16(kf0, qf, z, 0, 0, 0);
    f32x4 st1 = __builtin_amdgcn_mfma_f32_16x16x32_bf16(kf1, qf, z, 0, 0, 0);

    float s[8];
    s[0] = st0[0]; s[1] = st0[1]; s[2] = st0[2]; s[3] = st0[3];
    s[4] = st1[0]; s[5] = st1[1]; s[6] = st1[2]; s[7] = st1[3];
    float pm = fmaxf(fmaxf(fmaxf(s[0], s[1]), fmaxf(s[2], s[3])),
                     fmaxf(fmaxf(s[4], s[5]), fmaxf(s[6], s[7])));
    pm = fmaxf(pm, __shfl_xor(pm, 16));
    pm = fmaxf(pm, __shfl_xor(pm, 32));

    // defer-rescale (T13): only rescale when some query's max grew by > THR
    if (!__all(pm <= m + RESC_THR)) {
      float mnew = fmaxf(m, pm);
      float scale = exp2f((m - mnew) * LOG2E);
      lsum *= scale;
      #pragma unroll
      for (int ii = 0; ii < 16; ++ii) {
        acc[ii][0] *= scale; acc[ii][1] *= scale;
        acc[ii][2] *= scale; acc[ii][3] *= scale;
      }
      m = mnew;
    }

    float psum = 0.f;
    s16x8 pf;
    #pragma unroll
    for (int j = 0; j < 8; ++j) {
      float p = exp2f((s[j] - m) * LOG2E);
      psum += p;
      pf[j] = bf16s(p);
    }
    psum += __shfl_xor(psum, 16);
    psum += __shfl_xor(psum, 32);
    lsum += psum;

    #pragma unroll
    for (int ct = 0; ct < 16; ++ct) {
      s16x8 vf = *(const s16x8*)(vb + ct * 512);
      acc[ct] = __builtin_amdgcn_mfma_f32_16x16x32_bf16(vf, pf, acc[ct], 0, 0, 0);
    }
  }

  // ---- cross-wave combine ----
  comb_m[wave][lane] = m;
  comb_l[wave][lane] = lsum;
  __syncthreads();
  float M = fmaxf(fmaxf(comb_m[0][lane], comb_m[1][lane]),
                  fmaxf(comb_m[2][lane], comb_m[3][lane]));
  float L = 0.f;
  #pragma unroll
  for (int w2 = 0; w2 < 4; ++w2)
    L += comb_l[w2][lane] * exp2f((comb_m[w2][lane] - M) * LOG2E);
  float myscale = exp2f((m - M) * LOG2E);
  float rn = gamma[0] / L;
  int n = qt * 16 + c;

  for (int chunk = 0; chunk < 4; ++chunk) {
    #pragma unroll
    for (int q = 0; q < 4; ++q) {
      int ct = chunk * 4 + q;
      f32x4 a = acc[ct];
      a[0] *= myscale; a[1] *= myscale; a[2] *= myscale; a[3] *= myscale;
      *(f32x4*)&sumbuf[wave][q][lane][0] = a;
    }
    __syncthreads();
    f32x4 ssum = *(const f32x4*)&sumbuf[0][wave][lane][0];
    #pragma unroll
    for (int w2 = 1; w2 < 4; ++w2) {
      f32x4 t2 = *(const f32x4*)&sumbuf[w2][wave][lane][0];
      ssum[0] += t2[0]; ssum[1] += t2[1]; ssum[2] += t2[2]; ssum[3] += t2[3];
    }
    int ct = chunk * 4 + wave;
    #pragma unroll
    for (int jj = 0; jj < 4; ++jj) {
      int cc = ct * 16 + g * 4 + jj;
      int idx = (b * C_ + cc) * N_ + n;
      out[idx] = rn * ssum[jj] + x[idx];
    }
    __syncthreads();
  }
}

extern "C" void kernel_launch(void* const* d_in, const int* in_sizes, int n_in,
                              void* d_out, int out_size, void* d_ws, size_t ws_size,
                              hipStream_t stream) {
  const float* x     = (const float*)d_in[0];
  const float* gm    = (const float*)d_in[1];
  const float* Wq    = (const float*)d_in[2];
  const float* bq    = (const float*)d_in[3];
  const float* Wk    = (const float*)d_in[4];
  const float* bk    = (const float*)d_in[5];
  const float* Wv    = (const float*)d_in[6];
  const float* bv    = (const float*)d_in[7];
  const float* gamma = (const float*)d_in[8];

  char*  ws    = (char*)d_ws;          // needs ~10.3 MB
  short* wfrag = (short*)(ws + WS_WFRAG);
  float* bias  = (float*)(ws + WS_BIAS);
  short* qs    = (short*)(ws + WS_Q);
  short* ksz   = (short*)(ws + WS_K);
  short* vs    = (short*)(ws + WS_V);
  float* out   = (float*)d_out;

  wprep_kernel<<<dim3(320), dim3(256), 0, stream>>>(Wq, Wk, Wv, bq, bk, bv, wfrag, bias);
  proj_kernel<<<dim3(1024), dim3(256), 0, stream>>>(x, wfrag, bias, gm, qs, ksz, vs);
  attn_kernel<<<dim3(1024), dim3(256), 0, stream>>>(qs, ksz, vs, x, gamma, out);
}

// Round 5
// 89.853 us; speedup vs baseline: 1.6932x; 1.6932x over previous
//
#include <hip/hip_runtime.h>
#include <hip/hip_bf16.h>
#include <cstdint>

typedef __attribute__((ext_vector_type(4)))  float f32x4;
typedef __attribute__((ext_vector_type(16))) float f32x16;
typedef __attribute__((ext_vector_type(8)))  short s16x8;

#define LOG2E 1.4426950408889634f
#define RESC_THR 8.0f

#define B_   4
#define C_   256
#define N_   4096
#define NT_  256    // 16-pixel tiles per batch (proj granularity)
#define MB_  128    // 32-key blocks per batch
#define QG_  128    // 32-query groups per batch

// workspace byte offsets
#define WS_WFRAG 0u          // 20*8*4*16*8 bf16   = 163840
#define WS_BIAS  163840u     // 320 f32            = 1280
#define WS_Q     262144u     // B*QG*2*64*8 bf16   = 1 MiB
#define WS_K     1310720u    // B*MB*2*64*8 bf16   = 1 MiB
#define WS_V     2359296u    // B*MB*8*2*64*8 bf16 = 8 MiB  (end 10747904)

__device__ __forceinline__ short bf16s(float f) {
  return (short)__bfloat16_as_ushort(__float2bfloat16(f));
}

// ---------------- pack W (320x256) into A-frag layout (16x16x32), gather bias ----------------
__global__ void wprep_kernel(const float* __restrict__ Wq, const float* __restrict__ Wk,
                             const float* __restrict__ Wv, const float* __restrict__ bq,
                             const float* __restrict__ bk, const float* __restrict__ bv,
                             short* __restrict__ wfrag, float* __restrict__ bias) {
  int d0 = blockIdx.x * 256 + threadIdx.x;         // 81920 = 20*8*4*16*8
  int d = d0;
  int j  = d & 7;  d >>= 3;
  int c  = d & 15; d >>= 4;
  int g  = d & 3;  d >>= 2;
  int ks = d & 7;  d >>= 3;
  int t  = d;
  int o  = t * 16 + c;
  int ch = ks * 32 + g * 8 + j;
  float w = (o < 32) ? Wq[o * 256 + ch] : (o < 64) ? Wk[(o - 32) * 256 + ch]
                                                   : Wv[(o - 64) * 256 + ch];
  wfrag[d0] = bf16s(w);
  if (d0 < 320) bias[d0] = (d0 < 32) ? bq[d0] : (d0 < 64) ? bk[d0 - 32] : bv[d0 - 64];
}

// ---------------- fused QKV projection (MFMA) + inline gate + 32x32-frag stores ----------------
// Q frag slot ((b*QG+qt)*2+s)*64+lane, elem j : Q[ch=16s+8*(lane>>5)+j][q=32qt+(lane&31)]
// K frag slot ((b*MB+mb)*2+s)*64+lane, elem j : K[ch=16s+8*(lane>>5)+j][key=32mb+(lane&31)]
// V frag slot (((b*MB+mb)*8+ct)*2+s)*64+lane, elem j :
//     V[ch=ct*32+(lane&31)][key=32mb+16s+f(8*(lane>>5)+j)],  f(k)=(k&3)+8*((k>>2)&1)+4*(k>>3)
__global__ __launch_bounds__(256) void proj_kernel(
    const float* __restrict__ x, const short* __restrict__ wfrag,
    const float* __restrict__ bias, const float* __restrict__ gm,
    short* __restrict__ qs, short* __restrict__ ksz, short* __restrict__ vs) {
  int b = blockIdx.x >> 8, nt = blockIdx.x & 255;
  int lane = threadIdx.x & 63, wave = threadIdx.x >> 6;
  int g = lane >> 4, c = lane & 15;
  int n = nt * 16 + c;

  // inline gate: bilinear align-corners 32->64 + sigmoid
  float gt;
  {
    int y = n >> 6, xp = n & 63;
    float fy = (float)(y * 31) / 63.0f;
    float fx = (float)(xp * 31) / 63.0f;
    int y0 = (int)fy, x0 = (int)fx;
    float wy = fy - (float)y0, wx = fx - (float)x0;
    int y1 = min(y0 + 1, 31), x1 = min(x0 + 1, 31);
    const float* p = gm + b * 1024;
    float v00 = p[y0 * 32 + x0], v01 = p[y0 * 32 + x1];
    float v10 = p[y1 * 32 + x0], v11 = p[y1 * 32 + x1];
    float top = v00 * (1.f - wx) + v01 * wx;
    float bot = v10 * (1.f - wx) + v11 * wx;
    float gv  = top * (1.f - wy) + bot * wy;
    gt = 1.0f + 1.0f / (1.0f + expf(-gv));
  }

  const float* xb = x + b * (C_ * N_) + n;
  s16x8 xf[8];
  #pragma unroll
  for (int ks = 0; ks < 8; ++ks) {
    int ch0 = ks * 32 + g * 8;
    s16x8 v;
    #pragma unroll
    for (int j = 0; j < 8; ++j) v[j] = bf16s(xb[(ch0 + j) * N_]);
    xf[ks] = v;
  }

  int qt32 = n >> 5, r = n & 31;                 // 32-wide group / within-group index
  for (int t = wave * 5; t < wave * 5 + 5; ++t) {
    f32x4 acc = {0.f, 0.f, 0.f, 0.f};
    #pragma unroll
    for (int ks = 0; ks < 8; ++ks) {
      s16x8 wf = *(const s16x8*)(wfrag + ((((t * 8 + ks) * 4 + g) * 16 + c) * 8));
      acc = __builtin_amdgcn_mfma_f32_16x16x32_bf16(wf, xf[ks], acc, 0, 0, 0);
    }
    #pragma unroll
    for (int jj = 0; jj < 4; ++jj) {
      int o = t * 16 + g * 4 + jj;               // D row = (lane>>4)*4+reg
      float val = (acc[jj] + bias[o]) * gt;      // D col = lane&15 = pixel
      short bv16 = bf16s(val);
      if (o < 64) {                               // Q or K
        int ch = o & 31;
        int s  = (ch >> 4) & 1, hi = (ch >> 3) & 1, j = ch & 7;
        short* dst = (o < 32) ? qs : ksz;
        dst[(((b * QG_ + qt32) * 2 + s) * 64 + hi * 32 + r) * 8 + j] = bv16;
      } else {                                    // V
        int cv = o - 64;
        int ct = cv >> 5, lam = cv & 31;
        int s  = (r >> 4) & 1, r4 = r & 15;
        int k  = (r4 & 3) | (((r4 >> 3) & 1) << 2) | (((r4 >> 2) & 1) << 3);
        int hi = k >> 3, j = k & 7;
        vs[((((size_t)(b * MB_ + qt32) * 8 + ct) * 2 + s) * 64 + hi * 32 + lam) * 8 + j] = bv16;
      }
    }
  }
}

// ---------------- flash attention, 32x32 MFMA, split-KV within block ----------------
// 512 blocks (4b x 128 qg), 4 waves. Wave w: kv-blocks mb = w+4i. 32 queries/wave.
__global__ __launch_bounds__(256, 2) void attn_kernel(
    const short* __restrict__ qs, const short* __restrict__ ksz,
    const short* __restrict__ vs, const float* __restrict__ x,
    const float* __restrict__ gamma, float* __restrict__ out) {
  __shared__ float comb_m[4][32];
  __shared__ float comb_l[4][32];
  __shared__ float sumbuf[4][16][4][64];          // [tile-in-phase][elem][wave][lane] = 64 KB

  int bid = blockIdx.x;
  int b  = (bid & 7) >> 1;                        // batch pinned to XCD pair
  int qg = ((bid >> 3) << 1) | (bid & 1);         // 0..127
  int tid = threadIdx.x, lane = tid & 63, wave = tid >> 6;
  int lq = lane & 31;

  const short* qb = qs + (size_t)(((b * QG_ + qg) * 2) * 64 + lane) * 8;
  s16x8 qf0 = *(const s16x8*)(qb);
  s16x8 qf1 = *(const s16x8*)(qb + 512);

  f32x16 acc[8];
  #pragma unroll
  for (int ct = 0; ct < 8; ++ct)
    #pragma unroll
    for (int e = 0; e < 16; ++e) acc[ct][e] = 0.f;
  float m = -3.0e38f, lsum = 0.f;

  const short* kb0 = ksz + (size_t)b * (MB_ * 1024) + lane * 8;
  const short* vb0 = vs  + (size_t)b * ((size_t)MB_ * 8192) + lane * 8;

  int mb = wave;
  s16x8 kf0 = *(const s16x8*)(kb0 + mb * 1024);
  s16x8 kf1 = *(const s16x8*)(kb0 + mb * 1024 + 512);

  for (int i = 0; i < 32; ++i) {
    const short* vb = vb0 + (size_t)mb * 8192;
    // issue all 16 V loads first (latency hides under QK + softmax)
    s16x8 vf[16];
    #pragma unroll
    for (int t = 0; t < 16; ++t) vf[t] = *(const s16x8*)(vb + t * 512);

    // S^T = K.Q over 32 channels (2 k-steps)
    f32x16 st;
    #pragma unroll
    for (int e = 0; e < 16; ++e) st[e] = 0.f;
    st = __builtin_amdgcn_mfma_f32_32x32x16_bf16(kf0, qf0, st, 0, 0, 0);
    st = __builtin_amdgcn_mfma_f32_32x32x16_bf16(kf1, qf1, st, 0, 0, 0);

    // prefetch next K block
    int mbn = (i < 31) ? (mb + 4) : wave;
    s16x8 nk0 = *(const s16x8*)(kb0 + mbn * 1024);
    s16x8 nk1 = *(const s16x8*)(kb0 + mbn * 1024 + 512);

    // softmax over 32 keys (16 local + lane^32 half)
    float pm = st[0];
    #pragma unroll
    for (int e = 1; e < 16; ++e) pm = fmaxf(pm, st[e]);
    pm = fmaxf(pm, __shfl_xor(pm, 32));

    if (!__all(pm <= m + RESC_THR)) {             // defer-rescale (T13)
      float mnew = fmaxf(m, pm);
      float scale = exp2f((m - mnew) * LOG2E);
      lsum *= scale;
      #pragma unroll
      for (int ct = 0; ct < 8; ++ct)
        #pragma unroll
        for (int e = 0; e < 16; ++e) acc[ct][e] *= scale;
      m = mnew;
    }

    float psum = 0.f;
    s16x8 pf0, pf1;
    #pragma unroll
    for (int j = 0; j < 8; ++j) {
      float p = exp2f((st[j] - m) * LOG2E);
      psum += p; pf0[j] = bf16s(p);
    }
    #pragma unroll
    for (int j = 0; j < 8; ++j) {
      float p = exp2f((st[8 + j] - m) * LOG2E);
      psum += p; pf1[j] = bf16s(p);
    }
    psum += __shfl_xor(psum, 32);
    lsum += psum;

    // O^T += V.P  (8 channel tiles x 2 k-steps)
    #pragma unroll
    for (int ct = 0; ct < 8; ++ct) {
      acc[ct] = __builtin_amdgcn_mfma_f32_32x32x16_bf16(vf[ct * 2],     pf0, acc[ct], 0, 0, 0);
      acc[ct] = __builtin_amdgcn_mfma_f32_32x32x16_bf16(vf[ct * 2 + 1], pf1, acc[ct], 0, 0, 0);
    }
    kf0 = nk0; kf1 = nk1; mb = mbn;
  }

  // ---- cross-wave combine ----
  if (lane < 32) { comb_m[wave][lq] = m; comb_l[wave][lq] = lsum; }
  __syncthreads();
  float M = fmaxf(fmaxf(comb_m[0][lq], comb_m[1][lq]),
                  fmaxf(comb_m[2][lq], comb_m[3][lq]));
  float L = 0.f;
  #pragma unroll
  for (int w2 = 0; w2 < 4; ++w2)
    L += comb_l[w2][lq] * exp2f((comb_m[w2][lq] - M) * LOG2E);
  float myscale = exp2f((m - M) * LOG2E);
  float rn = gamma[0] / L;
  int n = qg * 32 + lq;
  int hi = lane >> 5;

  for (int phase = 0; phase < 2; ++phase) {
    #pragma unroll
    for (int t = 0; t < 4; ++t) {
      #pragma unroll
      for (int e = 0; e < 16; ++e)
        sumbuf[t][e][wave][lane] = acc[phase * 4 + t][e] * myscale;
    }
    __syncthreads();
    int ct = phase * 4 + wave;
    #pragma unroll
    for (int e = 0; e < 16; ++e) {
      float ssum = sumbuf[wave][e][0][lane] + sumbuf[wave][e][1][lane]
                 + sumbuf[wave][e][2][lane] + sumbuf[wave][e][3][lane];
      int ch = ct * 32 + (e & 3) + 8 * (e >> 2) + 4 * hi;
      int idx = (b * C_ + ch) * N_ + n;
      out[idx] = rn * ssum + x[idx];
    }
    __syncthreads();
  }
}

extern "C" void kernel_launch(void* const* d_in, const int* in_sizes, int n_in,
                              void* d_out, int out_size, void* d_ws, size_t ws_size,
                              hipStream_t stream) {
  const float* x     = (const float*)d_in[0];
  const float* gm    = (const float*)d_in[1];
  const float* Wq    = (const float*)d_in[2];
  const float* bq    = (const float*)d_in[3];
  const float* Wk    = (const float*)d_in[4];
  const float* bk    = (const float*)d_in[5];
  const float* Wv    = (const float*)d_in[6];
  const float* bv    = (const float*)d_in[7];
  const float* gamma = (const float*)d_in[8];

  char*  ws    = (char*)d_ws;          // needs ~10.3 MB
  short* wfrag = (short*)(ws + WS_WFRAG);
  float* bias  = (float*)(ws + WS_BIAS);
  short* qs    = (short*)(ws + WS_Q);
  short* ksz   = (short*)(ws + WS_K);
  short* vs    = (short*)(ws + WS_V);
  float* out   = (float*)d_out;

  wprep_kernel<<<dim3(320), dim3(256), 0, stream>>>(Wq, Wk, Wv, bq, bk, bv, wfrag, bias);
  proj_kernel<<<dim3(1024), dim3(256), 0, stream>>>(x, wfrag, bias, gm, qs, ksz, vs);
  attn_kernel<<<dim3(512), dim3(256), 0, stream>>>(qs, ksz, vs, x, gamma, out);
}

// Round 6
// 88.962 us; speedup vs baseline: 1.7102x; 1.0100x over previous
//
#include <hip/hip_runtime.h>
#include <hip/hip_bf16.h>
#include <cstdint>

typedef __attribute__((ext_vector_type(4)))  float f32x4;
typedef __attribute__((ext_vector_type(16))) float f32x16;
typedef __attribute__((ext_vector_type(8)))  short s16x8;

#define LOG2E 1.4426950408889634f
#define RESC_THR 8.0f

#define B_   4
#define C_   256
#define N_   4096
#define NT_  256    // 16-pixel tiles per batch (proj granularity)
#define MB_  128    // 32-key blocks per batch
#define QG_  128    // 32-query groups per batch

// workspace byte offsets
#define WS_WFRAG 0u          // 20*8*4*16*8 bf16   = 163840
#define WS_BIAS  163840u     // 320 f32            = 1280
#define WS_Q     262144u     // B*QG*2*64*8 bf16   = 1 MiB
#define WS_K     1310720u    // B*MB*2*64*8 bf16   = 1 MiB
#define WS_V     2359296u    // B*MB*8*2*64*8 bf16 = 8 MiB  (end 10747904)

__device__ __forceinline__ short bf16s(float f) {
  return (short)__bfloat16_as_ushort(__float2bfloat16(f));
}

// ---------------- pack W (320x256) into A-frag layout (16x16x32), gather bias ----------------
__global__ void wprep_kernel(const float* __restrict__ Wq, const float* __restrict__ Wk,
                             const float* __restrict__ Wv, const float* __restrict__ bq,
                             const float* __restrict__ bk, const float* __restrict__ bv,
                             short* __restrict__ wfrag, float* __restrict__ bias) {
  int d0 = blockIdx.x * 256 + threadIdx.x;         // 81920 = 20*8*4*16*8
  int d = d0;
  int j  = d & 7;  d >>= 3;
  int c  = d & 15; d >>= 4;
  int g  = d & 3;  d >>= 2;
  int ks = d & 7;  d >>= 3;
  int t  = d;
  int o  = t * 16 + c;
  int ch = ks * 32 + g * 8 + j;
  float w = (o < 32) ? Wq[o * 256 + ch] : (o < 64) ? Wk[(o - 32) * 256 + ch]
                                                   : Wv[(o - 64) * 256 + ch];
  wfrag[d0] = bf16s(w);
  if (d0 < 320) bias[d0] = (d0 < 32) ? bq[d0] : (d0 < 64) ? bk[d0 - 32] : bv[d0 - 64];
}

// ---------------- fused QKV projection (MFMA) + inline gate + 32x32-frag stores ----------------
// Q frag slot ((b*QG+qt)*2+s)*64+lane, elem j : Q[ch=16s+8*(lane>>5)+j][q=32qt+(lane&31)]
// K frag slot ((b*MB+mb)*2+s)*64+lane, elem j : K[ch=16s+8*(lane>>5)+j][key=32mb+(lane&31)]
// V frag slot (((b*MB+mb)*8+ct)*2+s)*64+lane, elem j :
//     V[ch=ct*32+(lane&31)][key=32mb+16s+f(8*(lane>>5)+j)],  f(k)=(k&3)+8*((k>>2)&1)+4*(k>>3)
__global__ __launch_bounds__(256) void proj_kernel(
    const float* __restrict__ x, const short* __restrict__ wfrag,
    const float* __restrict__ bias, const float* __restrict__ gm,
    short* __restrict__ qs, short* __restrict__ ksz, short* __restrict__ vs) {
  int b = blockIdx.x >> 8, nt = blockIdx.x & 255;
  int lane = threadIdx.x & 63, wave = threadIdx.x >> 6;
  int g = lane >> 4, c = lane & 15;
  int n = nt * 16 + c;

  // inline gate: bilinear align-corners 32->64 + sigmoid
  float gt;
  {
    int y = n >> 6, xp = n & 63;
    float fy = (float)(y * 31) / 63.0f;
    float fx = (float)(xp * 31) / 63.0f;
    int y0 = (int)fy, x0 = (int)fx;
    float wy = fy - (float)y0, wx = fx - (float)x0;
    int y1 = min(y0 + 1, 31), x1 = min(x0 + 1, 31);
    const float* p = gm + b * 1024;
    float v00 = p[y0 * 32 + x0], v01 = p[y0 * 32 + x1];
    float v10 = p[y1 * 32 + x0], v11 = p[y1 * 32 + x1];
    float top = v00 * (1.f - wx) + v01 * wx;
    float bot = v10 * (1.f - wx) + v11 * wx;
    float gv  = top * (1.f - wy) + bot * wy;
    gt = 1.0f + 1.0f / (1.0f + expf(-gv));
  }

  const float* xb = x + b * (C_ * N_) + n;
  s16x8 xf[8];
  #pragma unroll
  for (int ks = 0; ks < 8; ++ks) {
    int ch0 = ks * 32 + g * 8;
    s16x8 v;
    #pragma unroll
    for (int j = 0; j < 8; ++j) v[j] = bf16s(xb[(ch0 + j) * N_]);
    xf[ks] = v;
  }

  int qt32 = n >> 5, r = n & 31;                 // 32-wide group / within-group index
  for (int t = wave * 5; t < wave * 5 + 5; ++t) {
    f32x4 acc = {0.f, 0.f, 0.f, 0.f};
    #pragma unroll
    for (int ks = 0; ks < 8; ++ks) {
      s16x8 wf = *(const s16x8*)(wfrag + ((((t * 8 + ks) * 4 + g) * 16 + c) * 8));
      acc = __builtin_amdgcn_mfma_f32_16x16x32_bf16(wf, xf[ks], acc, 0, 0, 0);
    }
    #pragma unroll
    for (int jj = 0; jj < 4; ++jj) {
      int o = t * 16 + g * 4 + jj;               // D row = (lane>>4)*4+reg
      float val = (acc[jj] + bias[o]) * gt;      // D col = lane&15 = pixel
      short bv16 = bf16s(val);
      if (o < 64) {                               // Q or K
        int ch = o & 31;
        int s  = (ch >> 4) & 1, hi = (ch >> 3) & 1, j = ch & 7;
        short* dst = (o < 32) ? qs : ksz;
        dst[(((b * QG_ + qt32) * 2 + s) * 64 + hi * 32 + r) * 8 + j] = bv16;
      } else {                                    // V
        int cv = o - 64;
        int ct = cv >> 5, lam = cv & 31;
        int s  = (r >> 4) & 1, r4 = r & 15;
        int k  = (r4 & 3) | (((r4 >> 3) & 1) << 2) | (((r4 >> 2) & 1) << 3);
        int hi = k >> 3, j = k & 7;
        vs[((((size_t)(b * MB_ + qt32) * 8 + ct) * 2 + s) * 64 + hi * 32 + lam) * 8 + j] = bv16;
      }
    }
  }
}

// ---------------- flash attention, 32x32 MFMA, paired q-tiles share K/V via L1 ----------------
// 256 blocks x 512 threads (8 waves): wave = (s<<1)|qi; q-tile qg = qp*2+qi,
// kv-split s: mb = s+4i. The qi=0/1 pair with equal s issues identical K/V
// addresses each iter (raw s_barrier lockstep, no vmcnt drain) -> L1 serves pair.
__global__ __launch_bounds__(512, 2) void attn_kernel(
    const short* __restrict__ qs, const short* __restrict__ ksz,
    const short* __restrict__ vs, const float* __restrict__ x,
    const float* __restrict__ gamma, float* __restrict__ out) {
  __shared__ float comb_m[8][32];
  __shared__ float comb_l[8][32];
  __shared__ float sumbuf[16][16][64];            // [(qi*2+t)*4+s][elem][lane] = 64 KB

  int bid = blockIdx.x;
  int b  = (bid & 7) >> 1;                        // batch pinned to XCD pair
  int qp = ((bid >> 3) << 1) | (bid & 1);         // 0..63
  int tid = threadIdx.x, lane = tid & 63, wave = tid >> 6;
  int qi = wave & 1, s = wave >> 1;
  int qg = qp * 2 + qi;                           // 0..127
  int lq = lane & 31, hi = lane >> 5;

  const short* qb = qs + (size_t)(((b * QG_ + qg) * 2) * 64 + lane) * 8;
  s16x8 qf0 = *(const s16x8*)(qb);
  s16x8 qf1 = *(const s16x8*)(qb + 512);

  f32x16 acc[8];
  #pragma unroll
  for (int ct = 0; ct < 8; ++ct)
    #pragma unroll
    for (int e = 0; e < 16; ++e) acc[ct][e] = 0.f;
  float m = -3.0e38f, lsum = 0.f;

  const short* kb0 = ksz + (size_t)b * (MB_ * 1024) + lane * 8;
  const short* vb0 = vs  + (size_t)b * ((size_t)MB_ * 8192) + lane * 8;

  int mb = s;
  s16x8 kf0 = *(const s16x8*)(kb0 + mb * 1024);
  s16x8 kf1 = *(const s16x8*)(kb0 + mb * 1024 + 512);
  s16x8 va[8];
  {
    const short* vb = vb0 + (size_t)mb * 8192;
    #pragma unroll
    for (int t = 0; t < 8; ++t) va[t] = *(const s16x8*)(vb + t * 512);
  }

  for (int i = 0; i < 32; ++i) {
    const short* vb = vb0 + (size_t)mb * 8192;
    // second-half V loads (consumed by PV 4..7; latency hidden under QK+softmax+PV0..3)
    s16x8 vb2[8];
    #pragma unroll
    for (int t = 0; t < 8; ++t) vb2[t] = *(const s16x8*)(vb + (8 + t) * 512);

    // S^T = K.Q over 32 channels (2 k-steps)
    f32x16 st;
    #pragma unroll
    for (int e = 0; e < 16; ++e) st[e] = 0.f;
    st = __builtin_amdgcn_mfma_f32_32x32x16_bf16(kf0, qf0, st, 0, 0, 0);
    st = __builtin_amdgcn_mfma_f32_32x32x16_bf16(kf1, qf1, st, 0, 0, 0);

    // prefetch next K block
    int mbn = (i < 31) ? (mb + 4) : s;
    s16x8 nk0 = *(const s16x8*)(kb0 + mbn * 1024);
    s16x8 nk1 = *(const s16x8*)(kb0 + mbn * 1024 + 512);

    // softmax over 32 keys (16 local + lane^32 half)
    float pm = st[0];
    #pragma unroll
    for (int e = 1; e < 16; ++e) pm = fmaxf(pm, st[e]);
    pm = fmaxf(pm, __shfl_xor(pm, 32));

    if (!__all(pm <= m + RESC_THR)) {             // defer-rescale (T13)
      float mnew = fmaxf(m, pm);
      float scale = exp2f((m - mnew) * LOG2E);
      lsum *= scale;
      #pragma unroll
      for (int ct = 0; ct < 8; ++ct)
        #pragma unroll
        for (int e = 0; e < 16; ++e) acc[ct][e] *= scale;
      m = mnew;
    }

    float psum = 0.f;
    s16x8 pf0, pf1;
    #pragma unroll
    for (int j = 0; j < 8; ++j) {
      float p = exp2f((st[j] - m) * LOG2E);
      psum += p; pf0[j] = bf16s(p);
    }
    #pragma unroll
    for (int j = 0; j < 8; ++j) {
      float p = exp2f((st[8 + j] - m) * LOG2E);
      psum += p; pf1[j] = bf16s(p);
    }
    psum += __shfl_xor(psum, 32);
    lsum += psum;

    // O^T += V.P  : first 4 channel tiles from va
    #pragma unroll
    for (int ct = 0; ct < 4; ++ct) {
      acc[ct] = __builtin_amdgcn_mfma_f32_32x32x16_bf16(va[ct * 2],     pf0, acc[ct], 0, 0, 0);
      acc[ct] = __builtin_amdgcn_mfma_f32_32x32x16_bf16(va[ct * 2 + 1], pf1, acc[ct], 0, 0, 0);
    }
    // refill va with NEXT iter's first half (overlaps PV 4..7)
    {
      const short* vbn = vb0 + (size_t)mbn * 8192;
      #pragma unroll
      for (int t = 0; t < 8; ++t) va[t] = *(const s16x8*)(vbn + t * 512);
    }
    #pragma unroll
    for (int ct = 4; ct < 8; ++ct) {
      acc[ct] = __builtin_amdgcn_mfma_f32_32x32x16_bf16(vb2[(ct - 4) * 2],     pf0, acc[ct], 0, 0, 0);
      acc[ct] = __builtin_amdgcn_mfma_f32_32x32x16_bf16(vb2[(ct - 4) * 2 + 1], pf1, acc[ct], 0, 0, 0);
    }
    kf0 = nk0; kf1 = nk1; mb = mbn;
    __builtin_amdgcn_s_barrier();                 // raw: lockstep, no vmcnt drain
  }

  // ---- cross-split combine (4 splits per q-tile) ----
  if (lane < 32) { comb_m[wave][lq] = m; comb_l[wave][lq] = lsum; }
  __syncthreads();
  float M = fmaxf(fmaxf(comb_m[qi][lq], comb_m[2 + qi][lq]),
                  fmaxf(comb_m[4 + qi][lq], comb_m[6 + qi][lq]));
  float L = 0.f;
  #pragma unroll
  for (int s2 = 0; s2 < 4; ++s2)
    L += comb_l[s2 * 2 + qi][lq] * exp2f((comb_m[s2 * 2 + qi][lq] - M) * LOG2E);
  float myscale = exp2f((m - M) * LOG2E);
  float rn = gamma[0] / L;
  int n = qg * 32 + lq;

  for (int p = 0; p < 4; ++p) {                   // 2 ct-tiles per phase
    #pragma unroll
    for (int t = 0; t < 2; ++t) {
      #pragma unroll
      for (int e = 0; e < 16; ++e)
        sumbuf[(qi * 2 + t) * 4 + s][e][lane] = acc[p * 2 + t][e] * myscale;
    }
    __syncthreads();
    if (s < 2) {                                  // reader: merge tile ct = p*2+s of q-tile qi
      int slot = (qi * 2 + s) * 4;
      int ct = p * 2 + s;
      #pragma unroll
      for (int e = 0; e < 16; ++e) {
        float ssum = sumbuf[slot][e][lane] + sumbuf[slot + 1][e][lane]
                   + sumbuf[slot + 2][e][lane] + sumbuf[slot + 3][e][lane];
        int ch = ct * 32 + (e & 3) + 8 * (e >> 2) + 4 * hi;
        int idx = (b * C_ + ch) * N_ + n;
        out[idx] = rn * ssum + x[idx];
      }
    }
    __syncthreads();
  }
}

extern "C" void kernel_launch(void* const* d_in, const int* in_sizes, int n_in,
                              void* d_out, int out_size, void* d_ws, size_t ws_size,
                              hipStream_t stream) {
  const float* x     = (const float*)d_in[0];
  const float* gm    = (const float*)d_in[1];
  const float* Wq    = (const float*)d_in[2];
  const float* bq    = (const float*)d_in[3];
  const float* Wk    = (const float*)d_in[4];
  const float* bk    = (const float*)d_in[5];
  const float* Wv    = (const float*)d_in[6];
  const float* bv    = (const float*)d_in[7];
  const float* gamma = (const float*)d_in[8];

  char*  ws    = (char*)d_ws;          // needs ~10.3 MB
  short* wfrag = (short*)(ws + WS_WFRAG);
  float* bias  = (float*)(ws + WS_BIAS);
  short* qs    = (short*)(ws + WS_Q);
  short* ksz   = (short*)(ws + WS_K);
  short* vs    = (short*)(ws + WS_V);
  float* out   = (float*)d_out;

  wprep_kernel<<<dim3(320), dim3(256), 0, stream>>>(Wq, Wk, Wv, bq, bk, bv, wfrag, bias);
  proj_kernel<<<dim3(1024), dim3(256), 0, stream>>>(x, wfrag, bias, gm, qs, ksz, vs);
  attn_kernel<<<dim3(256), dim3(512), 0, stream>>>(qs, ksz, vs, x, gamma, out);
}